// Round 1
// baseline (610.999 us; speedup 1.0000x reference)
//
#include <hip/hip_runtime.h>
#include <hip/hip_bf16.h>

#define NEG_SLOPE 0.01f

// Order-preserving float->uint encoding for atomicMax. encf(0 buffer) == 0 is
// below any encoded finite value, so memset(0) is the max-identity.
__device__ __forceinline__ unsigned encf(float f) {
    unsigned u = __float_as_uint(f);
    return (u & 0x80000000u) ? ~u : (u | 0x80000000u);
}
__device__ __forceinline__ float decf(unsigned u) {
    return __uint_as_float((u & 0x80000000u) ? (u & 0x7FFFFFFFu) : ~u);
}

// K1: z = h @ W1^T  (N x 128 @ 128 x 64), plus s[n] = z[n].a_src, t[n] = z[n].a_dst
// Block 256 = 4 waves. Each block: 16 nodes. Wave w: nodes w*4..w*4+3, lane = out dim d.
__global__ __launch_bounds__(256) void k_gemm(
    const float* __restrict__ h, const float* __restrict__ W1,
    const float* __restrict__ Wa, float* __restrict__ z,
    float* __restrict__ s, float* __restrict__ t, int N)
{
    __shared__ float Ws[64 * 129];   // W1 padded: bank (d + k) % 32 -> 2-way, free
    __shared__ float hs[16 * 129];
    const int tid = threadIdx.x;
    const int nbase = blockIdx.x * 16;

    for (int idx = tid; idx < 64 * 128; idx += 256)
        Ws[(idx >> 7) * 129 + (idx & 127)] = W1[idx];
    for (int idx = tid; idx < 16 * 128; idx += 256) {
        int n = nbase + (idx >> 7);
        hs[(idx >> 7) * 129 + (idx & 127)] =
            (n < N) ? h[(size_t)n * 128 + (idx & 127)] : 0.f;
    }
    __syncthreads();

    const int w = tid >> 6, d = tid & 63;
    const float* __restrict__ wrow = &Ws[d * 129];
    const float* __restrict__ h0 = &hs[(w * 4 + 0) * 129];
    const float* __restrict__ h1 = &hs[(w * 4 + 1) * 129];
    const float* __restrict__ h2 = &hs[(w * 4 + 2) * 129];
    const float* __restrict__ h3 = &hs[(w * 4 + 3) * 129];
    float a0 = 0.f, a1 = 0.f, a2 = 0.f, a3 = 0.f;
#pragma unroll 8
    for (int k = 0; k < 128; ++k) {
        float wv = wrow[k];               // 2-way bank alias: free
        a0 = fmaf(h0[k], wv, a0);         // broadcast reads
        a1 = fmaf(h1[k], wv, a1);
        a2 = fmaf(h2[k], wv, a2);
        a3 = fmaf(h3[k], wv, a3);
    }

    const float asd = Wa[d];        // a_src[d]
    const float atd = Wa[64 + d];   // a_dst[d]
    float acc[4] = {a0, a1, a2, a3};
#pragma unroll
    for (int i = 0; i < 4; ++i) {
        const int n = nbase + w * 4 + i;
        if (n < N) z[(size_t)n * 64 + d] = acc[i];
        float ps = acc[i] * asd;
        float pt = acc[i] * atd;
#pragma unroll
        for (int off = 32; off; off >>= 1) {
            ps += __shfl_xor(ps, off);
            pt += __shfl_xor(pt, off);
        }
        if (d == 0 && n < N) { s[n] = ps; t[n] = pt; }
    }
}

// K2: emax[dst] = max over edges of leaky(e)
__global__ __launch_bounds__(256) void k_emax(
    const int* __restrict__ src, const int* __restrict__ dst,
    const float* __restrict__ s, const float* __restrict__ t,
    unsigned* __restrict__ emax, int E)
{
    int i = blockIdx.x * blockDim.x + threadIdx.x;
    const int stride = gridDim.x * blockDim.x;
    for (; i < E; i += stride) {
        int si = src[i], di = dst[i];
        float e = s[si] + t[di];
        e = (e >= 0.f) ? e : NEG_SLOPE * e;
        atomicMax(emax + di, encf(e));
    }
}

// K3: denom[dst] += exp(e - emax[dst])
__global__ __launch_bounds__(256) void k_denom(
    const int* __restrict__ src, const int* __restrict__ dst,
    const float* __restrict__ s, const float* __restrict__ t,
    const unsigned* __restrict__ emax, float* __restrict__ denom, int E)
{
    int i = blockIdx.x * blockDim.x + threadIdx.x;
    const int stride = gridDim.x * blockDim.x;
    for (; i < E; i += stride) {
        int si = src[i], di = dst[i];
        float e = s[si] + t[di];
        e = (e >= 0.f) ? e : NEG_SLOPE * e;
        float m = decf(emax[di]);
        atomicAdd(denom + di, __expf(e - m));
    }
}

// K4: h_out[dst] += alpha * z[src]; one wave per edge, lane = dim d.
__global__ __launch_bounds__(256) void k_aggr(
    const int* __restrict__ src, const int* __restrict__ dst,
    const float* __restrict__ s, const float* __restrict__ t,
    const unsigned* __restrict__ emax, const float* __restrict__ denom,
    const float* __restrict__ z, float* __restrict__ out, int E)
{
    const int e = blockIdx.x * 4 + (threadIdx.x >> 6);
    const int d = threadIdx.x & 63;
    if (e >= E) return;
    const int si = src[e], di = dst[e];
    float ev = s[si] + t[di];
    ev = (ev >= 0.f) ? ev : NEG_SLOPE * ev;
    const float m = decf(emax[di]);
    const float ex = __expf(ev - m);
    const float den = fmaxf(denom[di], 1e-16f);
    const float alpha = ex / den;
    const float val = alpha * z[(size_t)si * 64 + d];
    atomicAdd(out + (size_t)di * 64 + d, val);
}

extern "C" void kernel_launch(void* const* d_in, const int* in_sizes, int n_in,
                              void* d_out, int out_size, void* d_ws, size_t ws_size,
                              hipStream_t stream) {
    const float* h   = (const float*)d_in[0];
    const int*   src = (const int*)d_in[1];
    const int*   dst = (const int*)d_in[2];
    const float* W1  = (const float*)d_in[3];
    const float* Wa  = (const float*)d_in[4];
    float* out = (float*)d_out;

    const int N = in_sizes[0] / 128;
    const int E = in_sizes[1];

    // Workspace layout: z (N*64 f32) | s (N) | t (N) | emax (N u32) | denom (N)
    float*    z     = (float*)d_ws;
    float*    s     = z + (size_t)N * 64;
    float*    t     = s + N;
    unsigned* emax  = (unsigned*)(t + N);
    float*    denom = (float*)(emax + N);

    hipMemsetAsync(d_out, 0, (size_t)out_size * sizeof(float), stream);
    hipMemsetAsync(emax, 0, (size_t)N * sizeof(unsigned), stream);
    hipMemsetAsync(denom, 0, (size_t)N * sizeof(float), stream);

    k_gemm<<<(N + 15) / 16, 256, 0, stream>>>(h, W1, Wa, z, s, t, N);
    k_emax<<<1024, 256, 0, stream>>>(src, dst, s, t, emax, E);
    k_denom<<<1024, 256, 0, stream>>>(src, dst, s, t, emax, denom, E);
    k_aggr<<<(E + 3) / 4, 256, 0, stream>>>(src, dst, s, t, emax, denom, z, out, E);
}

// Round 2
// 397.319 us; speedup vs baseline: 1.5378x; 1.5378x over previous
//
#include <hip/hip_runtime.h>
#include <hip/hip_bf16.h>

#define NEG_SLOPE 0.01f

// K1: z = h @ W1^T  (N x 128 @ 128 x 64), plus s[n] = z[n].a_src, t[n] = z[n].a_dst
// Block 256 = 4 waves. Each block: 16 nodes. Wave w: nodes w*4..w*4+3, lane = out dim d.
__global__ __launch_bounds__(256) void k_gemm(
    const float* __restrict__ h, const float* __restrict__ W1,
    const float* __restrict__ Wa, float* __restrict__ z,
    float* __restrict__ s, float* __restrict__ t, int N)
{
    __shared__ float Ws[64 * 129];   // W1 padded: bank (d + k) % 32 -> 2-way, free
    __shared__ float hs[16 * 129];
    const int tid = threadIdx.x;
    const int nbase = blockIdx.x * 16;

    for (int idx = tid; idx < 64 * 128; idx += 256)
        Ws[(idx >> 7) * 129 + (idx & 127)] = W1[idx];
    for (int idx = tid; idx < 16 * 128; idx += 256) {
        int n = nbase + (idx >> 7);
        hs[(idx >> 7) * 129 + (idx & 127)] =
            (n < N) ? h[(size_t)n * 128 + (idx & 127)] : 0.f;
    }
    __syncthreads();

    const int w = tid >> 6, d = tid & 63;
    const float* __restrict__ wrow = &Ws[d * 129];
    const float* __restrict__ h0 = &hs[(w * 4 + 0) * 129];
    const float* __restrict__ h1 = &hs[(w * 4 + 1) * 129];
    const float* __restrict__ h2 = &hs[(w * 4 + 2) * 129];
    const float* __restrict__ h3 = &hs[(w * 4 + 3) * 129];
    float a0 = 0.f, a1 = 0.f, a2 = 0.f, a3 = 0.f;
#pragma unroll 8
    for (int k = 0; k < 128; ++k) {
        float wv = wrow[k];
        a0 = fmaf(h0[k], wv, a0);
        a1 = fmaf(h1[k], wv, a1);
        a2 = fmaf(h2[k], wv, a2);
        a3 = fmaf(h3[k], wv, a3);
    }

    const float asd = Wa[d];        // a_src[d]
    const float atd = Wa[64 + d];   // a_dst[d]
    float acc[4] = {a0, a1, a2, a3};
#pragma unroll
    for (int i = 0; i < 4; ++i) {
        const int n = nbase + w * 4 + i;
        if (n < N) z[(size_t)n * 64 + d] = acc[i];
        float ps = acc[i] * asd;
        float pt = acc[i] * atd;
#pragma unroll
        for (int off = 32; off; off >>= 1) {
            ps += __shfl_xor(ps, off);
            pt += __shfl_xor(pt, off);
        }
        if (d == 0 && n < N) { s[n] = ps; t[n] = pt; }
    }
}

// Histogram of dst
__global__ __launch_bounds__(256) void k_hist(
    const int* __restrict__ dst, unsigned* __restrict__ counts, int E)
{
    int i = blockIdx.x * blockDim.x + threadIdx.x;
    const int stride = gridDim.x * blockDim.x;
    for (; i < E; i += stride)
        atomicAdd(&counts[dst[i]], 1u);
}

// Scan step 1: per-256-chunk block sums
__global__ __launch_bounds__(256) void k_scan1(
    const unsigned* __restrict__ counts, unsigned* __restrict__ partials, int N)
{
    __shared__ unsigned sm[256];
    const int t = threadIdx.x;
    const int g = blockIdx.x * 256 + t;
    sm[t] = (g < N) ? counts[g] : 0u;
    __syncthreads();
    for (int off = 128; off; off >>= 1) {
        if (t < off) sm[t] += sm[t + off];
        __syncthreads();
    }
    if (t == 0) partials[blockIdx.x] = sm[0];
}

// Scan step 2: single block exclusive-scans the partials (NB <= 512)
__global__ __launch_bounds__(512) void k_scan2(unsigned* __restrict__ partials, int NB)
{
    __shared__ unsigned sm[512];
    const int t = threadIdx.x;
    unsigned orig = (t < NB) ? partials[t] : 0u;
    sm[t] = orig;
    __syncthreads();
    for (int off = 1; off < 512; off <<= 1) {
        unsigned v = (t >= off) ? sm[t - off] : 0u;
        __syncthreads();
        sm[t] += v;
        __syncthreads();
    }
    if (t < NB) partials[t] = sm[t] - orig;   // exclusive
}

// Scan step 3: per-chunk exclusive scan + block offset -> offsets, cursor
__global__ __launch_bounds__(256) void k_scan3(
    const unsigned* __restrict__ counts, const unsigned* __restrict__ partials,
    unsigned* __restrict__ offsets, unsigned* __restrict__ cursor, int N)
{
    __shared__ unsigned sm[256];
    const int t = threadIdx.x;
    const int g = blockIdx.x * 256 + t;
    unsigned orig = (g < N) ? counts[g] : 0u;
    sm[t] = orig;
    __syncthreads();
    for (int off = 1; off < 256; off <<= 1) {
        unsigned v = (t >= off) ? sm[t - off] : 0u;
        __syncthreads();
        sm[t] += v;
        __syncthreads();
    }
    if (g < N) {
        unsigned ex = partials[blockIdx.x] + sm[t] - orig;
        offsets[g] = ex;
        cursor[g]  = ex;
    }
}

// Fill CSR: edge_src[slot] = src index, bucketed by dst
__global__ __launch_bounds__(256) void k_scatter(
    const int* __restrict__ src, const int* __restrict__ dst,
    unsigned* __restrict__ cursor, unsigned* __restrict__ edge_src, int E)
{
    int i = blockIdx.x * blockDim.x + threadIdx.x;
    const int stride = gridDim.x * blockDim.x;
    for (; i < E; i += stride) {
        const int di = dst[i];
        const unsigned pos = atomicAdd(&cursor[di], 1u);
        edge_src[pos] = (unsigned)src[i];
    }
}

// Per-dst-node fused softmax + aggregate. One wave per node, lane = dim / edge.
__global__ __launch_bounds__(256) void k_node(
    const unsigned* __restrict__ offsets, const unsigned* __restrict__ counts,
    const unsigned* __restrict__ edge_src,
    const float* __restrict__ s, const float* __restrict__ t,
    const float* __restrict__ z, float* __restrict__ out, int N)
{
    const int node = blockIdx.x * 4 + (threadIdx.x >> 6);
    const int lane = threadIdx.x & 63;
    if (node >= N) return;

    const unsigned beg = offsets[node];
    const int cnt = (int)counts[node];
    if (cnt == 0) { out[(size_t)node * 64 + lane] = 0.f; return; }

    const float tn = t[node];
    float m = -__builtin_inff();
    float denom = 0.f;
    float acc = 0.f;

    for (int base = 0; base < cnt; base += 64) {
        const int rem = min(64, cnt - base);
        int sj = 0;
        float e = -__builtin_inff();
        if (lane < rem) {
            sj = (int)edge_src[beg + base + lane];
            e = s[sj] + tn;
            e = (e >= 0.f) ? e : NEG_SLOPE * e;
        }
        // wave max
        float cm = e;
#pragma unroll
        for (int off = 32; off; off >>= 1)
            cm = fmaxf(cm, __shfl_xor(cm, off));
        const float newm = fmaxf(m, cm);
        const float p = (lane < rem) ? __expf(e - newm) : 0.f;
        float ps = p;
#pragma unroll
        for (int off = 32; off; off >>= 1)
            ps += __shfl_xor(ps, off);
        const float scale = __expf(m - newm);   // first iter: exp(-inf)=0
        denom = denom * scale + ps;
        acc *= scale;
        for (int j = 0; j < rem; ++j) {
            const float pj = __shfl(p, j);
            const int sjj  = __shfl(sj, j);
            acc = fmaf(pj, z[(size_t)sjj * 64 + lane], acc);
        }
        m = newm;
    }
    out[(size_t)node * 64 + lane] = acc / fmaxf(denom, 1e-16f);
}

extern "C" void kernel_launch(void* const* d_in, const int* in_sizes, int n_in,
                              void* d_out, int out_size, void* d_ws, size_t ws_size,
                              hipStream_t stream) {
    const float* h   = (const float*)d_in[0];
    const int*   src = (const int*)d_in[1];
    const int*   dst = (const int*)d_in[2];
    const float* W1  = (const float*)d_in[3];
    const float* Wa  = (const float*)d_in[4];
    float* out = (float*)d_out;

    const int N = in_sizes[0] / 128;
    const int E = in_sizes[1];
    const int NB = (N + 255) / 256;          // scan chunks (<=512 supported)

    // Workspace: z | s | t | counts | offsets | cursor | partials(512) | edge_src
    float*    z        = (float*)d_ws;
    float*    s        = z + (size_t)N * 64;
    float*    t        = s + N;
    unsigned* counts   = (unsigned*)(t + N);
    unsigned* offsets  = counts + N;
    unsigned* cursor   = offsets + N;
    unsigned* partials = cursor + N;
    unsigned* edge_src = partials + 512;

    hipMemsetAsync(counts, 0, (size_t)N * sizeof(unsigned), stream);

    k_gemm<<<(N + 15) / 16, 256, 0, stream>>>(h, W1, Wa, z, s, t, N);
    k_hist<<<2048, 256, 0, stream>>>(dst, counts, E);
    k_scan1<<<NB, 256, 0, stream>>>(counts, partials, N);
    k_scan2<<<1, 512, 0, stream>>>(partials, NB);
    k_scan3<<<NB, 256, 0, stream>>>(counts, partials, offsets, cursor, N);
    k_scatter<<<2048, 256, 0, stream>>>(src, dst, cursor, edge_src, E);
    k_node<<<(N + 3) / 4, 256, 0, stream>>>(offsets, counts, edge_src, s, t, z, out, N);
}